// Round 1
// baseline (377.949 us; speedup 1.0000x reference)
//
#include <hip/hip_runtime.h>
#include <cstdint>
#include <cstddef>

#define BATCH 64
#define NIN   1024
#define CIN   256
#define NC    32
#define NCD   1024   // NC*DC
#define NJC   8      // j-chunks per batch
#define JCH   128    // NIN/NJC
#define SUBJ  16     // j per LDS stage
#define NSUB  8      // JCH/SUBJ
#define WTP   260    // padded wts row (float4-aligned, 4-way-conflict max)
#define T_EPS 1e-7f

// ---------- K1: partial column sums of x over j (iter-0 uniform routing) ----
__global__ __launch_bounds__(256) void k_colsum(const float* __restrict__ x,
                                                float* __restrict__ y0p) {
  const int b = blockIdx.y, jc = blockIdx.x, t = threadIdx.x;
  const float* xp = x + ((size_t)(b * NIN + jc * JCH)) * CIN + t;
  float a0 = 0.f, a1 = 0.f, a2 = 0.f, a3 = 0.f;
  for (int j = 0; j < JCH; j += 4) {
    a0 += xp[(size_t)(j + 0) * CIN];
    a1 += xp[(size_t)(j + 1) * CIN];
    a2 += xp[(size_t)(j + 2) * CIN];
    a3 += xp[(size_t)(j + 3) * CIN];
  }
  y0p[(b * NJC + jc) * CIN + t] = (a0 + a1) + (a2 + a3);
}

__device__ __forceinline__ float grp8_sum(float v) {
  v += __shfl_xor(v, 1);
  v += __shfl_xor(v, 2);
  v += __shfl_xor(v, 4);
  return v;
}

// squash a float4 per thread; 8 lanes (t%8) share capsule i = t/8
__device__ __forceinline__ float4 squash4(float4 s) {
  float s2 = s.x*s.x + s.y*s.y + s.z*s.z + s.w*s.w;
  s2 = grp8_sum(s2);
  float inv = rsqrtf(s2 + T_EPS);
  float4 o; o.x = s.x*inv; o.y = s.y*inv; o.z = s.z*inv; o.w = s.w*inv;
  return o;
}

// w~[b,i,c] = sum_k W[c, i*32+k] * out[b,i,k];  t indexes c (0..255)
__device__ __forceinline__ void wtilde_store(const float* outs, const float4* W4,
                                             float* __restrict__ wt, int b, int t) {
  const float4* o4 = (const float4*)outs;
  for (int i = 0; i < NC; ++i) {
    float acc = 0.f;
    #pragma unroll
    for (int k4 = 0; k4 < 8; ++k4) {
      float4 w = W4[t * (NCD / 4) + i * 8 + k4];
      float4 o = o4[i * 8 + k4];
      acc += w.x*o.x + w.y*o.y + w.z*o.z + w.w*o.w;
    }
    wt[((size_t)b * NC + i) * CIN + t] = acc;
  }
}

// ---------- K2: iter-0 s = (1/32)*(colsum_x)@W, squash, then w~ ------------
__global__ __launch_bounds__(256) void k_squash0(const float* __restrict__ y0p,
                                                 const float* __restrict__ W,
                                                 float* __restrict__ wt) {
  const int b = blockIdx.x, t = threadIdx.x;
  __shared__ float ys[CIN];
  __shared__ float outs[NCD];
  float a = 0.f;
  #pragma unroll
  for (int p = 0; p < NJC; ++p) a += y0p[(b * NJC + p) * CIN + t];
  ys[t] = a * (1.f / 32.f);
  __syncthreads();
  const float4* W4 = (const float4*)W;
  float4 acc = make_float4(0.f, 0.f, 0.f, 0.f);
  for (int c = 0; c < CIN; ++c) {
    float yc = ys[c];
    float4 w = W4[c * (NCD / 4) + t];
    acc.x += yc*w.x; acc.y += yc*w.y; acc.z += yc*w.z; acc.w += yc*w.w;
  }
  float4 o = squash4(acc);
  *(float4*)&outs[t * 4] = o;
  __syncthreads();
  wtilde_store(outs, W4, wt, b, t);
}

// ---------- K3: generic s = y@W, squash; then w~ (iters 1) or out (iter 2) -
template <int WRITE_WT>
__global__ __launch_bounds__(256) void k_squash(const float* __restrict__ ypart,
                                                const float* __restrict__ W,
                                                float* __restrict__ wt,
                                                float* __restrict__ outg) {
  const int b = blockIdx.x, t = threadIdx.x;
  __shared__ float ys[NC][CIN + 1];
  __shared__ float outs[NCD];
  for (int r = 0; r < NC; ++r) {
    float a = 0.f;
    #pragma unroll
    for (int p = 0; p < NJC; ++p)
      a += ypart[(((size_t)b * NJC + p) * NC + r) * CIN + t];
    ys[r][t] = a;
  }
  __syncthreads();
  const int i = t >> 3;
  const float4* W4 = (const float4*)W;
  float4 acc = make_float4(0.f, 0.f, 0.f, 0.f);
  for (int c = 0; c < CIN; ++c) {
    float yc = ys[i][c];
    float4 w = W4[c * (NCD / 4) + t];
    acc.x += yc*w.x; acc.y += yc*w.y; acc.z += yc*w.z; acc.w += yc*w.w;
  }
  float4 o = squash4(acc);
  if (WRITE_WT) {
    *(float4*)&outs[t * 4] = o;
    __syncthreads();
    wtilde_store(outs, W4, wt, b, t);
  } else {
    ((float4*)outg)[b * (NCD / 4) + t] = o;
  }
}

// ---------- K4: fused  b = x@w~^T -> softmax(i) -> y += c^T@x --------------
__global__ __launch_bounds__(256) void k_fused(const float* __restrict__ x,
                                               const float* __restrict__ wt,
                                               float* __restrict__ ypart) {
  const int b = blockIdx.y, jc = blockIdx.x, t = threadIdx.x;
  __shared__ float wts[NC][WTP];     // 33.3 KB
  __shared__ float xs[SUBJ][CIN];    // 16 KB
  __shared__ float cs[SUBJ][33];     // 2.1 KB
  {
    const float4* wtg = (const float4*)(wt + (size_t)b * NC * CIN);
    #pragma unroll
    for (int q = 0; q < 8; ++q) {
      int f = q * 256 + t;                 // 0..2047 float4s
      float4 v = wtg[f];
      *(float4*)&wts[f >> 6][(f & 63) * 4] = v;
    }
  }
  const int i  = t & 31;   // capsule, fixed for this thread in both phases
  const int sl = t >> 5;   // j-slot (phase A) / c-block (phase B)
  float4 accB[8];
  #pragma unroll
  for (int q = 0; q < 8; ++q) accB[q] = make_float4(0.f, 0.f, 0.f, 0.f);

  for (int sub = 0; sub < NSUB; ++sub) {
    __syncthreads();  // protect xs/cs from previous sub-chunk readers
    const float4* xg =
        (const float4*)(x + ((size_t)(b * NIN + jc * JCH + sub * SUBJ)) * CIN);
    #pragma unroll
    for (int q = 0; q < 4; ++q) {
      int f = q * 256 + t;                 // 0..1023 float4s
      *(float4*)&xs[f >> 6][(f & 63) * 4] = xg[f];
    }
    __syncthreads();
    // phase A: b1 = x[j]@w~[i] for j = sl and j = 8+sl
    float b1 = 0.f, b2 = 0.f;
    #pragma unroll 8
    for (int c4 = 0; c4 < 64; ++c4) {
      float4 w  = *(const float4*)&wts[i][c4 * 4];
      float4 xa = *(const float4*)&xs[sl][c4 * 4];
      float4 xb = *(const float4*)&xs[8 + sl][c4 * 4];
      b1 += w.x*xa.x + w.y*xa.y + w.z*xa.z + w.w*xa.w;
      b2 += w.x*xb.x + w.y*xb.y + w.z*xb.z + w.w*xb.w;
    }
    // softmax over the 32 capsules: each 32-lane half-wave holds one j
    float m1 = b1, m2 = b2;
    #pragma unroll
    for (int m = 1; m < 32; m <<= 1) {
      m1 = fmaxf(m1, __shfl_xor(m1, m));
      m2 = fmaxf(m2, __shfl_xor(m2, m));
    }
    float e1 = __expf(b1 - m1), e2 = __expf(b2 - m2);
    float s1 = e1, s2 = e2;
    #pragma unroll
    for (int m = 1; m < 32; m <<= 1) {
      s1 += __shfl_xor(s1, m);
      s2 += __shfl_xor(s2, m);
    }
    cs[sl][i]     = e1 / s1;
    cs[8 + sl][i] = e2 / s2;
    __syncthreads();
    // phase B: y[i, sl*32 .. +31] += sum_j c[j,i] * x[j, :]
    #pragma unroll
    for (int j = 0; j < SUBJ; ++j) {
      float cv = cs[j][i];
      #pragma unroll
      for (int q = 0; q < 8; ++q) {
        float4 xv = *(const float4*)&xs[j][sl * 32 + q * 4];
        accB[q].x += cv * xv.x; accB[q].y += cv * xv.y;
        accB[q].z += cv * xv.z; accB[q].w += cv * xv.w;
      }
    }
  }
  float* yp = ypart + (((size_t)b * NJC + jc) * NC + i) * CIN + sl * 32;
  #pragma unroll
  for (int q = 0; q < 8; ++q) *(float4*)&yp[q * 4] = accB[q];
}

extern "C" void kernel_launch(void* const* d_in, const int* in_sizes, int n_in,
                              void* d_out, int out_size, void* d_ws, size_t ws_size,
                              hipStream_t stream) {
  (void)in_sizes; (void)n_in; (void)out_size; (void)ws_size;
  const float* x = (const float*)d_in[0];
  const float* W = (const float*)d_in[1];
  float* out = (float*)d_out;
  char* ws = (char*)d_ws;
  // ws layout: y0p 512 KB | wt 2 MB | ypart 16 MB  (total ~18.5 MB)
  float* y0p   = (float*)(ws);
  float* wt    = (float*)(ws + (512u << 10));
  float* ypart = (float*)(ws + (512u << 10) + (2u << 20));

  dim3 gchunks(NJC, BATCH);
  k_colsum<<<gchunks, 256, 0, stream>>>(x, y0p);
  k_squash0<<<BATCH, 256, 0, stream>>>(y0p, W, wt);            // iter 0
  k_fused<<<gchunks, 256, 0, stream>>>(x, wt, ypart);          // iter 1 routing
  k_squash<1><<<BATCH, 256, 0, stream>>>(ypart, W, wt, nullptr);
  k_fused<<<gchunks, 256, 0, stream>>>(x, wt, ypart);          // iter 2 routing
  k_squash<0><<<BATCH, 256, 0, stream>>>(ypart, W, nullptr, out);
}

// Round 2
// 260.995 us; speedup vs baseline: 1.4481x; 1.4481x over previous
//
#include <hip/hip_runtime.h>
#include <cstdint>
#include <cstddef>

#define BATCH 64
#define NIN   1024
#define CIN   256
#define NC    32
#define NJC   16     // j-chunks per batch
#define JCH   64     // NIN/NJC
#define SUBJ  16     // j per LDS stage
#define NSUB  4      // JCH/SUBJ
#define WTPH  260    // padded wts row in bf16 shorts (520B: 8B-aligned, 2-way-conflict = free)
#define T_EPS 1e-7f

__device__ __forceinline__ unsigned short bf16rne(float f) {
  unsigned int u = __float_as_uint(f);
  u += 0x7FFFu + ((u >> 16) & 1u);
  return (unsigned short)(u >> 16);
}
__device__ __forceinline__ float bf2f(unsigned short h) {
  return __uint_as_float(((unsigned int)h) << 16);
}

// ---------- K1: partial column sums of x over j (iter-0 uniform routing) ----
__global__ __launch_bounds__(256) void k_colsum(const float* __restrict__ x,
                                                float* __restrict__ y0p) {
  const int b = blockIdx.y, jc = blockIdx.x, t = threadIdx.x;
  const float* xp = x + ((size_t)(b * NIN + jc * JCH)) * CIN + t;
  float a0 = 0.f, a1 = 0.f, a2 = 0.f, a3 = 0.f;
  for (int j = 0; j < JCH; j += 4) {
    a0 += xp[(size_t)(j + 0) * CIN];
    a1 += xp[(size_t)(j + 1) * CIN];
    a2 += xp[(size_t)(j + 2) * CIN];
    a3 += xp[(size_t)(j + 3) * CIN];
  }
  y0p[(b * NJC + jc) * CIN + t] = (a0 + a1) + (a2 + a3);
}

// ---------- K2: fused y-reduce -> s = y@W_i -> squash -> wt or out ----------
// grid (i=NC, b=BATCH); block 256. MODE 0: yin=y0p fp32 (i-independent).
// MODE 1: yin=ypart bf16, write wt. MODE 2: yin=ypart bf16, write out.
template <int MODE>
__global__ __launch_bounds__(256) void k_post(const void* __restrict__ yin,
                                              const float* __restrict__ W,
                                              float* __restrict__ wtout,
                                              float* __restrict__ outg) {
  const int i = blockIdx.x, b = blockIdx.y, t = threadIdx.x;
  __shared__ float Wl[CIN][36];   // W[c, i*32+k]; stride 36 -> 16B-aligned rows
  __shared__ float ys[CIN];
  __shared__ float sred[8][32];
  __shared__ float os[NC];
  // stage W block for capsule i (each 8-lane group reads 128B contiguous)
  const float4* W4 = (const float4*)W;
  #pragma unroll
  for (int q = 0; q < 8; ++q) {
    int f = q * 256 + t;            // 0..2047
    int c = f >> 3, k4 = f & 7;
    float4 v = W4[c * (NC * 8) + i * 8 + k4];
    *(float4*)&Wl[c][k4 * 4] = v;
  }
  // reduce partial y for this (b, i)
  float a = 0.f;
  if (MODE == 0) {
    const float* y0p = (const float*)yin;
    #pragma unroll
    for (int p = 0; p < NJC; ++p) a += y0p[(b * NJC + p) * CIN + t];
    a *= (1.f / 32.f);
  } else {
    const unsigned short* yp = (const unsigned short*)yin;
    #pragma unroll
    for (int p = 0; p < NJC; ++p)
      a += bf2f(yp[(((size_t)b * NJC + p) * NC + i) * CIN + t]);
  }
  ys[t] = a;
  __syncthreads();
  // s[k] = sum_c ys[c] * Wl[c][k]; 8 c-groups of 32, k = t&31
  {
    const int k = t & 31, g = t >> 5;
    float ps = 0.f;
    #pragma unroll
    for (int cc = 0; cc < 32; ++cc) {
      int c = g * 32 + cc;
      ps += ys[c] * Wl[c][k];     // banks (4c+k)%32: conflict-free
    }
    sred[g][k] = ps;
  }
  __syncthreads();
  const int k = t & 31;
  float s = 0.f;
  #pragma unroll
  for (int g = 0; g < 8; ++g) s += sred[g][k];
  float s2 = s * s;
  #pragma unroll
  for (int m = 1; m < 32; m <<= 1) s2 += __shfl_xor(s2, m);
  float o = s * rsqrtf(s2 + T_EPS);
  if (MODE == 2) {
    if (t < 32) outg[((size_t)b * NC + i) * 32 + t] = o;
  } else {
    if (t < 32) os[t] = o;
    __syncthreads();
    // wt[b,i,c] = sum_k W[c,ik] * o[k];  c = t
    float acc = 0.f;
    #pragma unroll
    for (int kk = 0; kk < 32; ++kk) acc += Wl[t][kk] * os[kk];
    wtout[((size_t)b * NC + i) * CIN + t] = acc;
  }
}

// ---------- K3: fused  b = x@wt^T -> softmax(i) -> ypart += c^T@x ----------
__global__ __launch_bounds__(256, 4) void k_fused(const float* __restrict__ x,
                                                  const float* __restrict__ wt,
                                                  unsigned short* __restrict__ ypart) {
  const int b = blockIdx.y, jc = blockIdx.x, t = threadIdx.x;
  __shared__ unsigned short wts[NC][WTPH];  // bf16, 16.6 KB
  __shared__ float xs[SUBJ][CIN];           // 16 KB
  __shared__ float cs[SUBJ][33];            // 2.1 KB   total 35.1 KB -> 4 blk/CU
  {  // stage wt -> bf16 LDS
    const float4* wtg = (const float4*)(wt + (size_t)b * NC * CIN);
    #pragma unroll
    for (int q = 0; q < 8; ++q) {
      int f = q * 256 + t;                  // 0..2047 float4s
      float4 v = wtg[f];
      ushort4 h;
      h.x = bf16rne(v.x); h.y = bf16rne(v.y);
      h.z = bf16rne(v.z); h.w = bf16rne(v.w);
      *(ushort4*)&wts[f >> 6][(f & 63) * 4] = h;
    }
  }
  const int i  = t & 31;   // capsule (phase A logits & phase B row)
  const int sl = t >> 5;   // j-slot (phase A) / c-block (phase B)
  float4 accB[8];
  #pragma unroll
  for (int q = 0; q < 8; ++q) accB[q] = make_float4(0.f, 0.f, 0.f, 0.f);

  // register prefetch of sub-chunk 0
  const float4* xg0 = (const float4*)(x + ((size_t)(b * NIN + jc * JCH)) * CIN);
  float4 xp[4];
  #pragma unroll
  for (int q = 0; q < 4; ++q) xp[q] = xg0[q * 256 + t];

  for (int sub = 0; sub < NSUB; ++sub) {
    __syncthreads();  // xs/cs free (prev phase B done)
    #pragma unroll
    for (int q = 0; q < 4; ++q) {
      int f = q * 256 + t;                  // 0..1023 float4s
      *(float4*)&xs[f >> 6][(f & 63) * 4] = xp[q];
    }
    if (sub + 1 < NSUB) {                   // prefetch next chunk; waited on
      const float4* xg = xg0 + (size_t)(sub + 1) * (SUBJ * CIN / 4);
      #pragma unroll
      for (int q = 0; q < 4; ++q) xp[q] = xg[q * 256 + t];
    }
    __syncthreads();
    // phase A: logits for j = sl and j = 8+sl  (xs reads are 2-addr broadcasts)
    float b1 = 0.f, b2 = 0.f;
    #pragma unroll 8
    for (int c4 = 0; c4 < 64; ++c4) {
      uint2 wp = *(const uint2*)&wts[i][c4 * 4];
      float4 xa = *(const float4*)&xs[sl][c4 * 4];
      float4 xb = *(const float4*)&xs[8 + sl][c4 * 4];
      float w0 = __uint_as_float(wp.x << 16);
      float w1 = __uint_as_float(wp.x & 0xFFFF0000u);
      float w2 = __uint_as_float(wp.y << 16);
      float w3 = __uint_as_float(wp.y & 0xFFFF0000u);
      b1 += w0 * xa.x + w1 * xa.y + w2 * xa.z + w3 * xa.w;
      b2 += w0 * xb.x + w1 * xb.y + w2 * xb.z + w3 * xb.w;
    }
    // softmax over 32 capsules within each 32-lane half-wave
    float m1 = b1, m2 = b2;
    #pragma unroll
    for (int m = 1; m < 32; m <<= 1) {
      m1 = fmaxf(m1, __shfl_xor(m1, m));
      m2 = fmaxf(m2, __shfl_xor(m2, m));
    }
    float e1 = __expf(b1 - m1), e2 = __expf(b2 - m2);
    float s1 = e1, s2 = e2;
    #pragma unroll
    for (int m = 1; m < 32; m <<= 1) {
      s1 += __shfl_xor(s1, m);
      s2 += __shfl_xor(s2, m);
    }
    cs[sl][i]     = e1 / s1;
    cs[8 + sl][i] = e2 / s2;
    __syncthreads();
    // phase B: y[i, sl*32..+31] += sum_j c[j,i] * x[j,:]
    #pragma unroll
    for (int j = 0; j < SUBJ; ++j) {
      float cv = cs[j][i];
      #pragma unroll
      for (int q = 0; q < 8; ++q) {
        float4 xv = *(const float4*)&xs[j][sl * 32 + q * 4];
        accB[q].x += cv * xv.x; accB[q].y += cv * xv.y;
        accB[q].z += cv * xv.z; accB[q].w += cv * xv.w;
      }
    }
  }
  // epilogue: bf16 partials
  unsigned short* yp =
      ypart + (((size_t)(b * NJC + jc) * NC + i) * CIN) + sl * 32;
  #pragma unroll
  for (int q = 0; q < 8; ++q) {
    ushort4 h;
    h.x = bf16rne(accB[q].x); h.y = bf16rne(accB[q].y);
    h.z = bf16rne(accB[q].z); h.w = bf16rne(accB[q].w);
    *(ushort4*)&yp[q * 4] = h;
  }
}

extern "C" void kernel_launch(void* const* d_in, const int* in_sizes, int n_in,
                              void* d_out, int out_size, void* d_ws, size_t ws_size,
                              hipStream_t stream) {
  (void)in_sizes; (void)n_in; (void)out_size; (void)ws_size;
  const float* x = (const float*)d_in[0];
  const float* W = (const float*)d_in[1];
  float* out = (float*)d_out;
  char* ws = (char*)d_ws;
  // ws layout: wt 2MB | ypart 16MB (bf16 [64][16][32][256]); y0p aliases ypart
  float* wt = (float*)ws;
  unsigned short* ypart = (unsigned short*)(ws + (2u << 20));
  float* y0p = (float*)(ws + (2u << 20));   // dead before first k_fused write

  dim3 gchunks(NJC, BATCH);   // (16, 64)
  dim3 gpost(NC, BATCH);      // (32, 64)
  k_colsum<<<gchunks, 256, 0, stream>>>(x, y0p);
  k_post<0><<<gpost, 256, 0, stream>>>(y0p, W, wt, nullptr);     // iter 0
  k_fused<<<gchunks, 256, 0, stream>>>(x, wt, ypart);            // iter 1 routing
  k_post<1><<<gpost, 256, 0, stream>>>(ypart, W, wt, nullptr);
  k_fused<<<gchunks, 256, 0, stream>>>(x, wt, ypart);            // iter 2 routing
  k_post<2><<<gpost, 256, 0, stream>>>(ypart, W, nullptr, out);
}